// Round 1
// baseline (1387.935 us; speedup 1.0000x reference)
//
#include <hip/hip_runtime.h>
#include <hip/hip_bf16.h>

// GptOss grouped experts: per-expert [2048 x 2880] x [5760 x 2880]^T -> swiglu
// -> x [2880 x 2880]^T. Strategy: fp32->bf16 pre-convert into d_ws, then two
// m97-structure bf16 MFMA GEMMs (128x128 / 128x96 tiles, BK=64,
// global_load_lds width 16, 2-barrier K-loop). SwiGLU fused into GEMM1
// epilogue via __shfl_xor pairing of even/odd h-columns.

#define TT   16384
#define DIM_ 2880
#define HID_ 2880
#define NE   8
#define TPE  2048
#define KDIM 2880

typedef __attribute__((ext_vector_type(8))) short short8;
typedef __attribute__((ext_vector_type(4))) float f32x4;

__device__ __forceinline__ unsigned short f2bf(float f) {
  unsigned u = __builtin_bit_cast(unsigned, f);
  u += 0x7fffu + ((u >> 16) & 1u);   // round-to-nearest-even
  return (unsigned short)(u >> 16);
}

__global__ void __launch_bounds__(256) cvt_f32_bf16(const float* __restrict__ src,
                                                    unsigned short* __restrict__ dst,
                                                    long n) {
  long i = ((long)blockIdx.x * 256 + threadIdx.x) * 8;
  if (i >= n) return;
  float4 a = *(const float4*)(src + i);
  float4 b = *(const float4*)(src + i + 4);
  union { unsigned short u[8]; short8 v; } r;
  r.u[0] = f2bf(a.x); r.u[1] = f2bf(a.y); r.u[2] = f2bf(a.z); r.u[3] = f2bf(a.w);
  r.u[4] = f2bf(b.x); r.u[5] = f2bf(b.y); r.u[6] = f2bf(b.z); r.u[7] = f2bf(b.w);
  *(short8*)(dst + i) = r.v;
}

// C = A(MxK) * B(NxK)^T, bf16 inputs, fp32 accum. Grid: (N/BN, M/128, E).
// 4 waves (2x2), per-wave 64 x (FN*16) output, 16x16x32 bf16 MFMA.
template<int BN, int FN, bool FUSE_SWIGLU>
__global__ void __launch_bounds__(256) gemm_bt(const unsigned short* __restrict__ A,
                                               const unsigned short* __restrict__ B,
                                               const float* __restrict__ bias,
                                               void* __restrict__ Cout,
                                               int M, int N) {
  constexpr int BM = 128, BK = 64;
  const int tid  = threadIdx.x;
  const int lane = tid & 63;
  const int wid  = tid >> 6;
  const int wr   = wid >> 1, wc = wid & 1;
  const int e    = blockIdx.z;
  const int m0   = blockIdx.y * BM;
  const int n0   = blockIdx.x * BN;

  __shared__ unsigned short As[BM * BK];   // [row][k] linear (global_load_lds: no pad)
  __shared__ unsigned short Bs[BN * BK];

  const unsigned short* Ae = A + (size_t)e * M * KDIM + (size_t)m0 * KDIM;
  const unsigned short* Be = B + (size_t)e * N * KDIM + (size_t)n0 * KDIM;

  f32x4 acc[4][FN] = {};

  const int srow = tid >> 3;          // staging: 8 lanes per row, 16B each
  const int scol = (tid & 7) * 8;     // k-elements

  for (int kt = 0; kt < KDIM / BK; ++kt) {
    const unsigned short* ak = Ae + kt * BK + scol;
    const unsigned short* bk = Be + kt * BK + scol;
#pragma unroll
    for (int j = 0; j < BM / 32; ++j)
      __builtin_amdgcn_global_load_lds(
          (const __attribute__((address_space(1))) unsigned int*)(ak + (size_t)(j * 32 + srow) * KDIM),
          (__attribute__((address_space(3))) unsigned int*)(&As[j * 2048 + tid * 8]),
          16, 0, 0);
#pragma unroll
    for (int j = 0; j < BN / 32; ++j)
      __builtin_amdgcn_global_load_lds(
          (const __attribute__((address_space(1))) unsigned int*)(bk + (size_t)(j * 32 + srow) * KDIM),
          (__attribute__((address_space(3))) unsigned int*)(&Bs[j * 2048 + tid * 8]),
          16, 0, 0);
    __syncthreads();   // compiler drains vmcnt before s_barrier

#pragma unroll
    for (int ks = 0; ks < 2; ++ks) {
      short8 af[4];
#pragma unroll
      for (int fm = 0; fm < 4; ++fm)
        af[fm] = *(const short8*)&As[(wr * 64 + fm * 16 + (lane & 15)) * BK + ks * 32 + (lane >> 4) * 8];
#pragma unroll
      for (int fn = 0; fn < FN; ++fn) {
        short8 bf = *(const short8*)&Bs[(wc * (FN * 16) + fn * 16 + (lane & 15)) * BK + ks * 32 + (lane >> 4) * 8];
#pragma unroll
        for (int fm = 0; fm < 4; ++fm)
          acc[fm][fn] = __builtin_amdgcn_mfma_f32_16x16x32_bf16(af[fm], bf, acc[fm][fn], 0, 0, 0);
      }
    }
    __syncthreads();
  }

  const float* be = bias + (size_t)e * N;
  if constexpr (FUSE_SWIGLU) {
    // h columns: even = glu, odd = lin. Pair adjacent lanes; even lanes store
    // activated column col/2 as bf16. 8 even lanes -> 8 consecutive bf16 (16B).
    unsigned short* ha = (unsigned short*)Cout + (size_t)e * M * (N / 2);
#pragma unroll
    for (int fm = 0; fm < 4; ++fm)
#pragma unroll
      for (int fn = 0; fn < FN; ++fn) {
        const int col = n0 + wc * (FN * 16) + fn * 16 + (lane & 15);
        const float bc = be[col];
#pragma unroll
        for (int j = 0; j < 4; ++j) {
          const int row = m0 + wr * 64 + fm * 16 + (lane >> 4) * 4 + j;
          float v = acc[fm][fn][j] + bc;
          float p = __shfl_xor(v, 1);   // partner column (all lanes execute)
          if (!(lane & 1)) {
            float g  = fminf(v, 7.0f);
            float l2 = fminf(fmaxf(p, -7.0f), 7.0f);
            float act = g / (1.0f + __expf(-1.702f * g)) * (l2 + 1.0f);
            ha[(size_t)row * (N / 2) + (col >> 1)] = f2bf(act);
          }
        }
      }
  } else {
    float* out = (float*)Cout + (size_t)e * M * N;
#pragma unroll
    for (int fm = 0; fm < 4; ++fm)
#pragma unroll
      for (int fn = 0; fn < FN; ++fn) {
        const int col = n0 + wc * (FN * 16) + fn * 16 + (lane & 15);
        const float bc = be[col];
#pragma unroll
        for (int j = 0; j < 4; ++j) {
          const int row = m0 + wr * 64 + fm * 16 + (lane >> 4) * 4 + j;
          out[(size_t)row * N + col] = acc[fm][fn][j] + bc;
        }
      }
  }
}

extern "C" void kernel_launch(void* const* d_in, const int* in_sizes, int n_in,
                              void* d_out, int out_size, void* d_ws, size_t ws_size,
                              hipStream_t stream) {
  const float* x  = (const float*)d_in[0];
  // d_in[1] = num_tokens_per_expert: fixed T/E split, unused (reference ignores it)
  const float* w1 = (const float*)d_in[2];
  const float* b1 = (const float*)d_in[3];
  const float* w2 = (const float*)d_in[4];
  const float* b2 = (const float*)d_in[5];

  // workspace layout (bf16): xb | w1b | w2b | ha   (~587 MB total)
  unsigned short* xb  = (unsigned short*)d_ws;
  unsigned short* w1b = xb  + (size_t)TT * DIM_;
  unsigned short* w2b = w1b + (size_t)NE * 2 * HID_ * DIM_;
  unsigned short* ha  = w2b + (size_t)NE * DIM_ * HID_;

  const long nx = (long)TT * DIM_;             // 47,185,920
  const long n1 = (long)NE * 2 * HID_ * DIM_;  // 132,710,400
  const long n2 = (long)NE * DIM_ * HID_;      // 66,355,200
  cvt_f32_bf16<<<(int)(nx / 2048), 256, 0, stream>>>(x,  xb,  nx);
  cvt_f32_bf16<<<(int)(n1 / 2048), 256, 0, stream>>>(w1, w1b, n1);
  cvt_f32_bf16<<<(int)(n2 / 2048), 256, 0, stream>>>(w2, w2b, n2);

  // GEMM1 + bias + swiglu -> ha (bf16, [E][2048][2880])
  dim3 g1(2 * HID_ / 128, TPE / 128, NE);      // (45, 16, 8)
  gemm_bt<128, 4, true><<<g1, 256, 0, stream>>>(xb, w1b, b1, ha, TPE, 2 * HID_);

  // GEMM2 + bias -> out (fp32, [T][2880])
  dim3 g2(DIM_ / 96, TPE / 128, NE);           // (30, 16, 8)
  gemm_bt<96, 3, false><<<g2, 256, 0, stream>>>(ha, w2b, b2, (float*)d_out, TPE, DIM_);
}

// Round 3
// 1252.309 us; speedup vs baseline: 1.1083x; 1.1083x over previous
//
#include <hip/hip_runtime.h>
#include <hip/hip_bf16.h>

// GptOss grouped experts, round 2 (resubmit after infra failure):
// 256x192-tile 8-wave bf16 MFMA GEMM with counted-vmcnt software pipeline
// (T3/T4), XOR-swizzled LDS (T2, via inverse-swizzled global source since
// global_load_lds writes linearly), setprio around MFMA (T5), per-expert
// bijective XCD swizzle (T1). SwiGLU fused into GEMM1 epilogue.
// fp32->bf16 pre-convert in d_ws.

#define TT   16384
#define DIM_ 2880
#define HID_ 2880
#define NE   8
#define TPE  2048
#define KDIM 2880   // K for both GEMMs
#define NT   45     // KDIM / 64

typedef __attribute__((ext_vector_type(8))) short short8;
typedef __attribute__((ext_vector_type(4))) float f32x4;

__device__ __forceinline__ unsigned short f2bf(float f) {
  unsigned u = __builtin_bit_cast(unsigned, f);
  u += 0x7fffu + ((u >> 16) & 1u);   // round-to-nearest-even
  return (unsigned short)(u >> 16);
}

__global__ void __launch_bounds__(256) cvt_f32_bf16(const float* __restrict__ src,
                                                    unsigned short* __restrict__ dst,
                                                    long n) {
  long i = ((long)blockIdx.x * 256 + threadIdx.x) * 8;
  if (i >= n) return;
  float4 a = *(const float4*)(src + i);
  float4 b = *(const float4*)(src + i + 4);
  union { unsigned short u[8]; short8 v; } r;
  r.u[0] = f2bf(a.x); r.u[1] = f2bf(a.y); r.u[2] = f2bf(a.z); r.u[3] = f2bf(a.w);
  r.u[4] = f2bf(b.x); r.u[5] = f2bf(b.y); r.u[6] = f2bf(b.z); r.u[7] = f2bf(b.w);
  *(short8*)(dst + i) = r.v;
}

// C = A(MxK) * B(NxK)^T, bf16 in, fp32 accum. BM=256, BN=192, BK=64.
// 512 threads = 8 waves (2M x 4N); per-wave 128x48 output (FM=8, FNW=3).
// Grid: (ntm*ntn, 1, E). LDS: dbuf x (A 32KB + B 24KB) = 112 KB -> 1 blk/CU.
template<bool FUSE_SWIGLU>
__global__ void __launch_bounds__(512, 2) gemm8(const unsigned short* __restrict__ A,
                                                const unsigned short* __restrict__ B,
                                                const float* __restrict__ bias,
                                                void* __restrict__ Cout,
                                                int M, int N) {
  __shared__ unsigned short As[2][256 * 64];
  __shared__ unsigned short Bs[2][192 * 64];

  const int tid  = threadIdx.x;
  const int lane = tid & 63;
  const int wid  = tid >> 6;
  const int wr   = wid >> 2;        // 0..1
  const int wc   = wid & 3;         // 0..3
  const int e    = blockIdx.z;

  // T1: per-expert bijective XCD swizzle (per_e % 8 == 0 for both GEMMs).
  const int ntn   = N / 192;
  const int ntm   = M / 256;
  const int per_e = ntn * ntm;
  const int bid   = blockIdx.x;
  const int swz   = (bid & 7) * (per_e >> 3) + (bid >> 3);
  const int m0    = (swz / ntn) * 256;
  const int n0    = (swz % ntn) * 192;

  // ---- staging addressing (T2: inverse-swizzled global source, linear LDS dest)
  const int srow = tid >> 3;                                   // 0..63
  const int scol = (((tid & 7) ^ (srow & 7)) << 4) >> 1;       // elements, mult of 8
  const unsigned short* Aexp = A + ((size_t)e * M + m0 + srow) * KDIM + scol;
  const unsigned short* Bexp = B + ((size_t)e * N + n0 + srow) * KDIM + scol;

  auto stage = [&](int buf, int kt) {
    const unsigned short* asrc = Aexp + (size_t)kt * 64;
#pragma unroll
    for (int j = 0; j < 4; ++j)
      __builtin_amdgcn_global_load_lds(
          (const __attribute__((address_space(1))) unsigned int*)(asrc + (size_t)(j * 64) * KDIM),
          (__attribute__((address_space(3))) unsigned int*)(&As[buf][j * 4096 + tid * 8]),
          16, 0, 0);
    const unsigned short* bsrc = Bexp + (size_t)kt * 64;
#pragma unroll
    for (int j = 0; j < 3; ++j)
      __builtin_amdgcn_global_load_lds(
          (const __attribute__((address_space(1))) unsigned int*)(bsrc + (size_t)(j * 64) * KDIM),
          (__attribute__((address_space(3))) unsigned int*)(&Bs[buf][j * 4096 + tid * 8]),
          16, 0, 0);
  };

  // ---- fragment-read addressing (swizzled)
  const int arow_off = (wr * 128 + (lane & 15)) * 128;   // bytes
  const int brow_off = (wc * 48  + (lane & 15)) * 128;   // bytes
  const int swzb = (lane & 7) << 4;
  const int kb   = ((lane >> 4) & 3) * 16;
  const int c0 = kb ^ swzb;          // kk=0 swizzled k-byte
  const int c1 = (64 + kb) ^ swzb;   // kk=1

  f32x4 acc[8][3] = {};

  // ---- prologue: tiles 0,1 in flight; wait tile 0 (7 of tile 1 remain)
  stage(0, 0);
  stage(1, 1);
  asm volatile("s_waitcnt vmcnt(7)" ::: "memory");
  __builtin_amdgcn_s_barrier();

  for (int t = 0; t < NT; ++t) {
    const int cur = t & 1;
    const char* aB = (const char*)(&As[cur][0]) + arow_off;
    const char* bB = (const char*)(&Bs[cur][0]) + brow_off;

    short8 a0[8], a1[8], b0[3], b1[3];
#pragma unroll
    for (int fm = 0; fm < 8; ++fm) {
      a0[fm] = *(const short8*)(aB + fm * 2048 + c0);
      a1[fm] = *(const short8*)(aB + fm * 2048 + c1);
    }
#pragma unroll
    for (int fn = 0; fn < 3; ++fn) {
      b0[fn] = *(const short8*)(bB + fn * 2048 + c0);
      b1[fn] = *(const short8*)(bB + fn * 2048 + c1);
    }

    // kk=0 MFMAs overlap kk=1 ds_reads (compiler counted lgkmcnt)
#pragma unroll
    for (int fn = 0; fn < 3; ++fn)
#pragma unroll
      for (int fm = 0; fm < 8; ++fm)
        acc[fm][fn] = __builtin_amdgcn_mfma_f32_16x16x32_bf16(a0[fm], b0[fn], acc[fm][fn], 0, 0, 0);

    // all our ds_reads done -> buffer free; barrier makes it true for all waves
    asm volatile("s_waitcnt lgkmcnt(0)" ::: "memory");
    __builtin_amdgcn_s_barrier();

    const bool more = (t + 2 < NT);
    if (more) stage(cur, t + 2);     // overwrite vacated buffer

    __builtin_amdgcn_s_setprio(1);
#pragma unroll
    for (int fn = 0; fn < 3; ++fn)
#pragma unroll
      for (int fm = 0; fm < 8; ++fm)
        acc[fm][fn] = __builtin_amdgcn_mfma_f32_16x16x32_bf16(a1[fm], b1[fn], acc[fm][fn], 0, 0, 0);
    __builtin_amdgcn_s_setprio(0);

    // counted vmcnt: wait tile t+1 complete, leave tile t+2's 7 loads in flight
    if (more) asm volatile("s_waitcnt vmcnt(7)" ::: "memory");
    else      asm volatile("s_waitcnt vmcnt(0)" ::: "memory");
    __builtin_amdgcn_s_barrier();
  }

  // ---- epilogue
  const float* be = bias + (size_t)e * N;
  if constexpr (FUSE_SWIGLU) {
    unsigned short* ha = (unsigned short*)Cout + (size_t)e * M * (N >> 1);
#pragma unroll
    for (int fm = 0; fm < 8; ++fm)
#pragma unroll
      for (int fn = 0; fn < 3; ++fn) {
        const int col = n0 + wc * 48 + fn * 16 + (lane & 15);
        const float bc = be[col];
#pragma unroll
        for (int j = 0; j < 4; ++j) {
          const int row = m0 + wr * 128 + fm * 16 + (lane >> 4) * 4 + j;
          float v = acc[fm][fn][j] + bc;
          float p = __shfl_xor(v, 1);   // partner column (all lanes execute)
          if (!(lane & 1)) {
            float g  = fminf(v, 7.0f);
            float l2 = fminf(fmaxf(p, -7.0f), 7.0f);
            float act = g / (1.0f + __expf(-1.702f * g)) * (l2 + 1.0f);
            ha[(size_t)row * (N >> 1) + (col >> 1)] = f2bf(act);
          }
        }
      }
  } else {
    float* out = (float*)Cout + (size_t)e * M * N;
#pragma unroll
    for (int fm = 0; fm < 8; ++fm)
#pragma unroll
      for (int fn = 0; fn < 3; ++fn) {
        const int col = n0 + wc * 48 + fn * 16 + (lane & 15);
        const float bc = be[col];
#pragma unroll
        for (int j = 0; j < 4; ++j) {
          const int row = m0 + wr * 128 + fm * 16 + (lane >> 4) * 4 + j;
          out[(size_t)row * N + col] = acc[fm][fn][j] + bc;
        }
      }
  }
}

extern "C" void kernel_launch(void* const* d_in, const int* in_sizes, int n_in,
                              void* d_out, int out_size, void* d_ws, size_t ws_size,
                              hipStream_t stream) {
  const float* x  = (const float*)d_in[0];
  // d_in[1] = num_tokens_per_expert: fixed T/E split (reference ignores it)
  const float* w1 = (const float*)d_in[2];
  const float* b1 = (const float*)d_in[3];
  const float* w2 = (const float*)d_in[4];
  const float* b2 = (const float*)d_in[5];

  unsigned short* xb  = (unsigned short*)d_ws;
  unsigned short* w1b = xb  + (size_t)TT * DIM_;
  unsigned short* w2b = w1b + (size_t)NE * 2 * HID_ * DIM_;
  unsigned short* ha  = w2b + (size_t)NE * DIM_ * HID_;

  const long nx = (long)TT * DIM_;
  const long n1 = (long)NE * 2 * HID_ * DIM_;
  const long n2 = (long)NE * DIM_ * HID_;
  cvt_f32_bf16<<<(int)(nx / 2048), 256, 0, stream>>>(x,  xb,  nx);
  cvt_f32_bf16<<<(int)(n1 / 2048), 256, 0, stream>>>(w1, w1b, n1);
  cvt_f32_bf16<<<(int)(n2 / 2048), 256, 0, stream>>>(w2, w2b, n2);

  // GEMM1 + bias + swiglu -> ha (bf16 [E][2048][2880])
  dim3 g1((5760 / 192) * (TPE / 256), 1, NE);   // 240 per expert
  gemm8<true><<<g1, 512, 0, stream>>>(xb, w1b, b1, ha, TPE, 5760);

  // GEMM2 + bias -> out (fp32 [T][2880])
  dim3 g2((DIM_ / 192) * (TPE / 256), 1, NE);   // 120 per expert
  gemm8<false><<<g2, 512, 0, stream>>>(ha, w2b, b2, (float*)d_out, TPE, DIM_);
}